// Round 1
// baseline (1501.477 us; speedup 1.0000x reference)
//
#include <hip/hip_runtime.h>

#define NEG_SLOPE 0.2f

__device__ __forceinline__ float leaky(float v) { return v > 0.0f ? v : NEG_SLOPE * v; }

// Monotone float<->uint encoding: float order == unsigned order.
__device__ __forceinline__ unsigned enc_f(float f) {
    unsigned b = __float_as_uint(f);
    return (b & 0x80000000u) ? ~b : (b | 0x80000000u);
}
__device__ __forceinline__ float dec_f(unsigned k) {
    return (k & 0x80000000u) ? __uint_as_float(k ^ 0x80000000u) : __uint_as_float(~k);
}

// h = x @ W  ([N,FIN] x [FIN,32]); alpha_s = h . a_s; alpha_d = h . a_d;
// menc[i] seeded with enc(leaky(as+ad))  (self-loop logit) -- overwrites ws poison.
template <int FIN>
__global__ __launch_bounds__(256) void gemm_att(
    const float* __restrict__ x, const float* __restrict__ W,
    const float* __restrict__ a_s, const float* __restrict__ a_d,
    float* __restrict__ h, float* __restrict__ alpha_s,
    float* __restrict__ alpha_d, unsigned* __restrict__ menc, int N)
{
    __shared__ float Wl[FIN * 32];
    for (int i = threadIdx.x; i < FIN * 32; i += 256) Wl[i] = W[i];
    __syncthreads();
    const int col  = threadIdx.x & 31;
    const int row  = blockIdx.x * 8 + (threadIdx.x >> 5);
    const int rowc = row < N ? row : N - 1;   // keep all lanes active for shuffles
    const float* xr = x + (size_t)rowc * FIN;
    float acc = 0.0f;
#pragma unroll
    for (int f = 0; f < FIN; f += 4) {
        float4 xv = *(const float4*)(xr + f);   // broadcast across the 32-lane row group
        acc += xv.x * Wl[(f + 0) * 32 + col];
        acc += xv.y * Wl[(f + 1) * 32 + col];
        acc += xv.z * Wl[(f + 2) * 32 + col];
        acc += xv.w * Wl[(f + 3) * 32 + col];
    }
    float ps = acc * a_s[col];
    float pd = acc * a_d[col];
#pragma unroll
    for (int m = 16; m >= 1; m >>= 1) {        // reduce within each 32-lane half of wave64
        ps += __shfl_xor(ps, m);
        pd += __shfl_xor(pd, m);
    }
    if (row < N) {
        h[(size_t)row * 32 + col] = acc;
        if (col == 0) {
            alpha_s[row] = ps;
            alpha_d[row] = pd;
            menc[row]    = enc_f(leaky(ps + pd));
        }
    }
}

__global__ __launch_bounds__(256) void edge_max(
    const int* __restrict__ esrc, const int* __restrict__ edst,
    const float* __restrict__ alpha_s, const float* __restrict__ alpha_d,
    unsigned* __restrict__ menc, int E)
{
    int e = blockIdx.x * 256 + threadIdx.x;
    if (e >= E) return;
    int s = esrc[e], d = edst[e];
    atomicMax(menc + d, enc_f(leaky(alpha_s[s] + alpha_d[d])));
}

// Seed denom/acc with the self-loop contribution (plain stores -> poison-safe init).
__global__ __launch_bounds__(256) void node_init(
    const float* __restrict__ h, const float* __restrict__ alpha_s,
    const float* __restrict__ alpha_d, const unsigned* __restrict__ menc,
    float* __restrict__ denom, float* __restrict__ acc, int N)
{
    int t = blockIdx.x * 256 + threadIdx.x;
    int i = t >> 5, k = t & 31;
    if (i >= N) return;
    float m = dec_f(menc[i]);
    float w = __expf(leaky(alpha_s[i] + alpha_d[i]) - m);
    if (k == 0) denom[i] = w;
    acc[(size_t)i * 32 + k] = w * h[(size_t)i * 32 + k];
}

// 32 lanes per edge: lane k handles feature k (coalesced gather + atomic span).
__global__ __launch_bounds__(256) void edge_acc(
    const int* __restrict__ esrc, const int* __restrict__ edst,
    const float* __restrict__ alpha_s, const float* __restrict__ alpha_d,
    const unsigned* __restrict__ menc, const float* __restrict__ h,
    float* __restrict__ denom, float* __restrict__ acc, int E)
{
    long long t = (long long)blockIdx.x * 256 + threadIdx.x;
    int e = (int)(t >> 5);
    int k = (int)(t & 31);
    if (e >= E) return;
    int s = esrc[e], d = edst[e];
    float w = __expf(leaky(alpha_s[s] + alpha_d[d]) - dec_f(menc[d]));
    atomicAdd(acc + (size_t)d * 32 + k, w * h[(size_t)s * 32 + k]);
    if (k == 0) atomicAdd(denom + d, w);
}

__global__ __launch_bounds__(256) void node_fin(
    const float* __restrict__ acc, const float* __restrict__ denom,
    const float* __restrict__ bias, float* __restrict__ out, int N)
{
    int t = blockIdx.x * 256 + threadIdx.x;
    int i = t >> 5, k = t & 31;
    if (i >= N) return;
    float v = acc[(size_t)i * 32 + k] / denom[i] + bias[k];
    out[(size_t)i * 32 + k] = fmaxf(v, 0.0f);
}

__global__ __launch_bounds__(256) void final_gemm(
    const float* __restrict__ h, const float* __restrict__ Wf,
    const float* __restrict__ bf, float* __restrict__ out, int N)
{
    __shared__ float Wl[32 * 32];
    for (int i = threadIdx.x; i < 1024; i += 256) Wl[i] = Wf[i];
    __syncthreads();
    int col = threadIdx.x & 31;
    int row = blockIdx.x * 8 + (threadIdx.x >> 5);
    if (row >= N) return;
    const float* hr = h + (size_t)row * 32;
    float acc = bf[col];
#pragma unroll
    for (int j = 0; j < 32; ++j) acc += hr[j] * Wl[j * 32 + col];
    out[(size_t)row * 32 + col] = acc;
}

extern "C" void kernel_launch(void* const* d_in, const int* in_sizes, int n_in,
                              void* d_out, int out_size, void* d_ws, size_t ws_size,
                              hipStream_t stream)
{
    const float* x   = (const float*)d_in[0];
    const int*   ei  = (const int*)d_in[1];
    const float* W1  = (const float*)d_in[2];
    const float* a1s = (const float*)d_in[3];
    const float* a1d = (const float*)d_in[4];
    const float* b1  = (const float*)d_in[5];
    const float* W2  = (const float*)d_in[6];
    const float* a2s = (const float*)d_in[7];
    const float* a2d = (const float*)d_in[8];
    const float* b2  = (const float*)d_in[9];
    const float* Wf  = (const float*)d_in[10];
    const float* bf  = (const float*)d_in[11];

    const int N = in_sizes[0] / 128;
    const int E = in_sizes[1] / 2;
    const int* esrc = ei;
    const int* edst = ei + E;

    // Workspace layout (floats): h1 | acc | h2 | alpha_s | alpha_d | menc | denom
    float* ws = (float*)d_ws;
    float*    h1      = ws;
    float*    acc     = h1 + (size_t)N * 32;
    float*    h2      = acc + (size_t)N * 32;
    float*    alpha_s = h2 + (size_t)N * 32;
    float*    alpha_d = alpha_s + N;
    unsigned* menc    = (unsigned*)(alpha_d + N);
    float*    denom   = (float*)(menc + N);

    const int nb_rows   = (N + 7) / 8;
    const int nb_node   = (N * 32 + 255) / 256;
    const int nb_edge   = (E + 255) / 256;
    const int nb_edge32 = (int)(((long long)E * 32 + 255) / 256);

    // ---- layer 1 ----
    gemm_att<128><<<nb_rows, 256, 0, stream>>>(x, W1, a1s, a1d, h1, alpha_s, alpha_d, menc, N);
    edge_max<<<nb_edge, 256, 0, stream>>>(esrc, edst, alpha_s, alpha_d, menc, E);
    node_init<<<nb_node, 256, 0, stream>>>(h1, alpha_s, alpha_d, menc, denom, acc, N);
    edge_acc<<<nb_edge32, 256, 0, stream>>>(esrc, edst, alpha_s, alpha_d, menc, h1, denom, acc, E);
    node_fin<<<nb_node, 256, 0, stream>>>(acc, denom, b1, h2, N);

    // ---- layer 2 ----
    gemm_att<32><<<nb_rows, 256, 0, stream>>>(h2, W2, a2s, a2d, h1, alpha_s, alpha_d, menc, N);
    edge_max<<<nb_edge, 256, 0, stream>>>(esrc, edst, alpha_s, alpha_d, menc, E);
    node_init<<<nb_node, 256, 0, stream>>>(h1, alpha_s, alpha_d, menc, denom, acc, N);
    edge_acc<<<nb_edge32, 256, 0, stream>>>(esrc, edst, alpha_s, alpha_d, menc, h1, denom, acc, E);
    node_fin<<<nb_node, 256, 0, stream>>>(acc, denom, b2, h2, N);

    // ---- final linear ----
    final_gemm<<<nb_rows, 256, 0, stream>>>(h2, Wf, bf, (float*)d_out, N);
}

// Round 2
// 870.882 us; speedup vs baseline: 1.7241x; 1.7241x over previous
//
#include <hip/hip_runtime.h>

#define NEG_SLOPE 0.2f
#define SBLK 256

__device__ __forceinline__ float leaky(float v) { return v > 0.0f ? v : NEG_SLOPE * v; }

// ---------------- CSR build ----------------

__global__ __launch_bounds__(256) void k_zero(int* __restrict__ deg, int N) {
    int i = blockIdx.x * 256 + threadIdx.x;
    if (i < N) deg[i] = 0;
}

__global__ __launch_bounds__(256) void k_hist(const int* __restrict__ edst,
                                              int* __restrict__ deg, int E) {
    int e = blockIdx.x * 256 + threadIdx.x;
    if (e < E) atomicAdd(deg + edst[e], 1);
}

// per-block degree sums
__global__ __launch_bounds__(SBLK) void k_part(const int* __restrict__ deg,
                                               int* __restrict__ part, int N) {
    __shared__ int sm[SBLK];
    int i = blockIdx.x * SBLK + threadIdx.x;
    sm[threadIdx.x] = i < N ? deg[i] : 0;
    __syncthreads();
    for (int s = SBLK / 2; s > 0; s >>= 1) {
        if (threadIdx.x < s) sm[threadIdx.x] += sm[threadIdx.x + s];
        __syncthreads();
    }
    if (threadIdx.x == 0) part[blockIdx.x] = sm[0];
}

// exclusive scan of block partials (nb <= 1024), single block
__global__ __launch_bounds__(1024) void k_scanpart(int* __restrict__ part, int nb) {
    __shared__ int sm[1024];
    int t = threadIdx.x;
    int v = t < nb ? part[t] : 0;
    sm[t] = v;
    __syncthreads();
    for (int d = 1; d < 1024; d <<= 1) {
        int x = (t >= d) ? sm[t - d] : 0;
        __syncthreads();
        sm[t] += x;
        __syncthreads();
    }
    if (t < nb) part[t] = sm[t] - v;  // exclusive
}

// per-block exclusive scan + add block offset -> off[i]; zero deg (reused as cnt)
__global__ __launch_bounds__(SBLK) void k_scan3(int* __restrict__ deg,
                                                const int* __restrict__ part,
                                                int* __restrict__ off, int N, int E) {
    __shared__ int sm[SBLK];
    int i = blockIdx.x * SBLK + threadIdx.x;
    int v = i < N ? deg[i] : 0;
    sm[threadIdx.x] = v;
    __syncthreads();
    for (int d = 1; d < SBLK; d <<= 1) {
        int x = (threadIdx.x >= d) ? sm[threadIdx.x - d] : 0;
        __syncthreads();
        sm[threadIdx.x] += x;
        __syncthreads();
    }
    if (i < N) {
        off[i] = part[blockIdx.x] + sm[threadIdx.x] - v;  // global exclusive
        deg[i] = 0;                                        // becomes scatter cursor
    }
    if (i == N - 1) off[N] = E;
}

__global__ __launch_bounds__(256) void k_scatter(const int* __restrict__ esrc,
                                                 const int* __restrict__ edst,
                                                 const int* __restrict__ off,
                                                 int* __restrict__ cnt,
                                                 int* __restrict__ csr, int E) {
    int e = blockIdx.x * 256 + threadIdx.x;
    if (e >= E) return;
    int d = edst[e];
    int r = atomicAdd(cnt + d, 1);
    csr[off[d] + r] = esrc[e];
}

// ---------------- GAT layer kernels ----------------

// h = x @ W  ([N,FIN] x [FIN,32]); alpha_s = h . a_s; alpha_d = h . a_d
template <int FIN>
__global__ __launch_bounds__(256) void gemm_att(
    const float* __restrict__ x, const float* __restrict__ W,
    const float* __restrict__ a_s, const float* __restrict__ a_d,
    float* __restrict__ h, float* __restrict__ alpha_s,
    float* __restrict__ alpha_d, int N)
{
    __shared__ float Wl[FIN * 32];
    for (int i = threadIdx.x; i < FIN * 32; i += 256) Wl[i] = W[i];
    __syncthreads();
    const int col  = threadIdx.x & 31;
    const int row  = blockIdx.x * 8 + (threadIdx.x >> 5);
    const int rowc = row < N ? row : N - 1;   // keep all lanes active for shuffles
    const float* xr = x + (size_t)rowc * FIN;
    float acc = 0.0f;
#pragma unroll
    for (int f = 0; f < FIN; f += 4) {
        float4 xv = *(const float4*)(xr + f);
        acc += xv.x * Wl[(f + 0) * 32 + col];
        acc += xv.y * Wl[(f + 1) * 32 + col];
        acc += xv.z * Wl[(f + 2) * 32 + col];
        acc += xv.w * Wl[(f + 3) * 32 + col];
    }
    float ps = acc * a_s[col];
    float pd = acc * a_d[col];
#pragma unroll
    for (int m = 16; m >= 1; m >>= 1) {  // xor<32 stays within each 32-lane half
        ps += __shfl_xor(ps, m);
        pd += __shfl_xor(pd, m);
    }
    if (row < N) {
        h[(size_t)row * 32 + col] = acc;
        if (col == 0) {
            alpha_s[row] = ps;
            alpha_d[row] = pd;
        }
    }
}

// One 32-lane group per node; lane k = feature k. Gather-sum over incoming
// edges via CSR: softmax max-pass, then exp+weighted-accumulate in registers.
__global__ __launch_bounds__(256) void fused_agg(
    const int* __restrict__ csr, const int* __restrict__ off,
    const float* __restrict__ alpha_s, const float* __restrict__ alpha_d,
    const float* __restrict__ h, const float* __restrict__ bias,
    float* __restrict__ out, int N)
{
    int t = blockIdx.x * 256 + threadIdx.x;
    int i = t >> 5, k = t & 31;
    if (i >= N) return;
    int s0 = off[i], s1 = off[i + 1];
    float ad   = alpha_d[i];
    float slog = leaky(alpha_s[i] + ad);    // self-loop logit
    // pass 1: segment max (lanes stride over edges)
    float m = slog;
    for (int j = s0 + k; j < s1; j += 32)
        m = fmaxf(m, leaky(alpha_s[csr[j]] + ad));
#pragma unroll
    for (int d = 16; d >= 1; d >>= 1)
        m = fmaxf(m, __shfl_xor(m, d, 32));
    // pass 2: exp + weighted accumulate (serial over edges, 32 features wide)
    float w   = __expf(slog - m);
    float den = w;
    float acc = w * h[(size_t)i * 32 + k];
    for (int j = s0; j < s1; ++j) {
        int s = csr[j];
        float lw = __expf(leaky(alpha_s[s] + ad) - m);
        den += lw;
        acc += lw * h[(size_t)s * 32 + k];
    }
    float v = acc / den + bias[k];
    out[(size_t)i * 32 + k] = fmaxf(v, 0.0f);
}

__global__ __launch_bounds__(256) void final_gemm(
    const float* __restrict__ h, const float* __restrict__ Wf,
    const float* __restrict__ bf, float* __restrict__ out, int N)
{
    __shared__ float Wl[32 * 32];
    for (int i = threadIdx.x; i < 1024; i += 256) Wl[i] = Wf[i];
    __syncthreads();
    int col = threadIdx.x & 31;
    int row = blockIdx.x * 8 + (threadIdx.x >> 5);
    if (row >= N) return;
    const float* hr = h + (size_t)row * 32;
    float acc = bf[col];
#pragma unroll
    for (int j = 0; j < 32; ++j) acc += hr[j] * Wl[j * 32 + col];
    out[(size_t)row * 32 + col] = acc;
}

extern "C" void kernel_launch(void* const* d_in, const int* in_sizes, int n_in,
                              void* d_out, int out_size, void* d_ws, size_t ws_size,
                              hipStream_t stream)
{
    const float* x   = (const float*)d_in[0];
    const int*   ei  = (const int*)d_in[1];
    const float* W1  = (const float*)d_in[2];
    const float* a1s = (const float*)d_in[3];
    const float* a1d = (const float*)d_in[4];
    const float* b1  = (const float*)d_in[5];
    const float* W2  = (const float*)d_in[6];
    const float* a2s = (const float*)d_in[7];
    const float* a2d = (const float*)d_in[8];
    const float* b2  = (const float*)d_in[9];
    const float* Wf  = (const float*)d_in[10];
    const float* bf  = (const float*)d_in[11];

    const int N = in_sizes[0] / 128;
    const int E = in_sizes[1] / 2;
    const int* esrc = ei;
    const int* edst = ei + E;

    // Workspace (4B units): h1 32N | h2 32N | alpha_s N | alpha_d N |
    //                       deg N | off N+1 | part 1024 | csr E      (~39.6 MB)
    float* ws = (float*)d_ws;
    float* h1      = ws;
    float* h2      = h1 + (size_t)N * 32;
    float* alpha_s = h2 + (size_t)N * 32;
    float* alpha_d = alpha_s + N;
    int*   deg     = (int*)(alpha_d + N);   // later reused as scatter cursor
    int*   off     = deg + N;
    int*   part    = off + (N + 1);
    int*   csr     = part + 1024;

    const int nb_rows = (N + 7) / 8;
    const int nb_node = (N * 32 + 255) / 256;
    const int nb_edge = (E + 255) / 256;
    const int nb_seg  = (N + SBLK - 1) / SBLK;

    // ---- CSR build (once per launch, shared by both layers) ----
    k_zero    <<<(N + 255) / 256, 256, 0, stream>>>(deg, N);
    k_hist    <<<nb_edge, 256, 0, stream>>>(edst, deg, E);
    k_part    <<<nb_seg, SBLK, 0, stream>>>(deg, part, N);
    k_scanpart<<<1, 1024, 0, stream>>>(part, nb_seg);
    k_scan3   <<<nb_seg, SBLK, 0, stream>>>(deg, part, off, N, E);
    k_scatter <<<nb_edge, 256, 0, stream>>>(esrc, edst, off, deg, csr, E);

    // ---- layer 1 ----
    gemm_att<128><<<nb_rows, 256, 0, stream>>>(x, W1, a1s, a1d, h1, alpha_s, alpha_d, N);
    fused_agg<<<nb_node, 256, 0, stream>>>(csr, off, alpha_s, alpha_d, h1, b1, h2, N);

    // ---- layer 2 ----
    gemm_att<32><<<nb_rows, 256, 0, stream>>>(h2, W2, a2s, a2d, h1, alpha_s, alpha_d, N);
    fused_agg<<<nb_node, 256, 0, stream>>>(csr, off, alpha_s, alpha_d, h1, b2, h2, N);

    // ---- final linear ----
    final_gemm<<<nb_rows, 256, 0, stream>>>(h2, Wf, bf, (float*)d_out, N);
}